// Round 19
// baseline (204.156 us; speedup 1.0000x reference)
//
#include <hip/hip_runtime.h>
#include <hip/hip_bf16.h>

// ---------------- problem constants ----------------
// x: [B=8, N1=4, S=64, L=8192], PATCH=128 -> Lp=64, P=128, F=256, Lout=62
// out: [8,4,64,62,1] fp32

typedef _Float16 fp16_t;
typedef _Float16 fp16x8 __attribute__((ext_vector_type(8)));
typedef __fp16 pkh2 __attribute__((ext_vector_type(2)));   // cvt_pkrtz result type
typedef float f32x4 __attribute__((ext_vector_type(4)));

// ws float-word offsets
constexpr int WOFF_CONST = 32;    // 1 float
constexpr int WOFF_VF    = 64;    // 256 floats
constexpr int WOFF_VB    = 320;   // 256 floats
constexpr int WOFF_W1T   = 1024;                // f16 [2][4][256][32]
constexpr int WOFF_CWT   = WOFF_W1T + 32768;    // f16 [2][24][256][32] = 196608 words
constexpr int WOFF_CTHR  = WOFF_CWT + 196608;   // 512 uints, per-(b,s) cnt_thr
constexpr int WOFF_CPOS  = WOFF_CTHR + 512;     // 512 uints, per-(b,s) cnt_pos

constexpr int HBUF = 64 * 512;    // 32 KB per s-half

// silu via v_rcp (1 ulp): R13 PMC confirmed VALUBusy 52% -> 27% vs IEEE divide.
__device__ __forceinline__ float silu_f(float v) {
    return v * __builtin_amdgcn_rcpf(1.0f + __expf(-v));
}

// ---------------- prep (R18-verified): rowcount + weight pack -------------------
__global__ __launch_bounds__(256) void prep_kernel(
    const float* __restrict__ c,
    const float* __restrict__ W2f, const float* __restrict__ b2f,
    const float* __restrict__ W2b, const float* __restrict__ b2b,
    const float* __restrict__ Wr,  const float* __restrict__ br,
    const float* __restrict__ W1f, const float* __restrict__ W1b,
    const float* __restrict__ Cwf, const float* __restrict__ Cwb,
    float* __restrict__ wsf) {
    const int bid = blockIdx.x;
    const int tid = threadIdx.x;

    if (bid < 512) {
        const int b = bid >> 6, s = bid & 63;
        const float* cb = c + (size_t)b * 65536;

        __shared__ __align__(16) float rowv[1024];
        __shared__ float ms_sh, ss_sh;
        __shared__ unsigned int ls[8];
        *(float4*)&rowv[tid * 4] = *(const float4*)&cb[s * 1024 + tid * 4];
        __syncthreads();

        const int t = tid >> 2, part = tid & 3;
        const float4* src  = (const float4*)(cb + t * 1024 + part * 256);
        const float4* mine = (const float4*)(rowv + part * 256);
        float dot = 0.0f, sum = 0.0f, sq = 0.0f;
        #pragma unroll 8
        for (int i = 0; i < 64; ++i) {
            float4 a = mine[i];
            float4 bb = src[i];
            dot += a.x * bb.x + a.y * bb.y + a.z * bb.z + a.w * bb.w;
            sum += bb.x + bb.y + bb.z + bb.w;
            sq  += bb.x * bb.x + bb.y * bb.y + bb.z * bb.z + bb.w * bb.w;
        }
        dot += __shfl_down(dot, 2); dot += __shfl_down(dot, 1);
        sum += __shfl_down(sum, 2); sum += __shfl_down(sum, 1);
        sq  += __shfl_down(sq, 2);  sq  += __shfl_down(sq, 1);

        float mt = 0.0f, st = 0.0f;
        if (part == 0) {
            mt = sum * (1.0f / 1024.0f);
            st = sqrtf(fmaxf((sq - 1024.0f * mt * mt) * (1.0f / 1023.0f), 0.0f));
            if (t == s) { ms_sh = mt; ss_sh = st; }
        }
        __syncthreads();
        const float ms = ms_sh, ss = ss_sh;

        const bool valid = (part == 0) && (t != s);
        const float ctr = dot - 1024.0f * ms * mt;               // 1024*cov
        unsigned long long mthr = __ballot(valid && (ctr > 0.6f * 1024.0f * ss * st));
        unsigned long long mpos = __ballot(valid && (ctr > 0.0f));
        const int w = tid >> 6;
        if ((tid & 63) == 0) {
            ls[w]     = (unsigned int)__popcll(mthr);
            ls[4 + w] = (unsigned int)__popcll(mpos);
        }
        __syncthreads();
        if (tid == 0) {
            unsigned int* cthr = (unsigned int*)wsf + WOFF_CTHR;
            unsigned int* cpos = (unsigned int*)wsf + WOFF_CPOS;
            cthr[bid] = ls[0] + ls[1] + ls[2] + ls[3];
            cpos[bid] = ls[4] + ls[5] + ls[6] + ls[7];
        }
    } else if (bid < 560) {
        const int idx = bid - 512;
        const int d = idx / 24, ks = idx % 24;
        const float* Cw = d ? Cwb : Cwf;
        fp16_t* cwt = (fp16_t*)(wsf + WOFF_CWT) + d * 196608;
        const int base = ks * 32;
        const int k = base >> 8, i0 = base & 255;
        fp16x8 v[4];
        #pragma unroll
        for (int j = 0; j < 4; ++j)
            #pragma unroll
            for (int e = 0; e < 8; ++e)
                v[j][e] = (fp16_t)Cw[(tid * 256 + i0 + j * 8 + e) * 3 + k];
        fp16x8* dst = (fp16x8*)(cwt + (ks * 256 + tid) * 32);
        dst[0] = v[0]; dst[1] = v[1]; dst[2] = v[2]; dst[3] = v[3];
    } else if (bid < 568) {
        const int sl = bid - 560;
        const int d = sl >> 2, ks = sl & 3;
        const float* W1 = d ? W1b : W1f;
        fp16_t* w1t = (fp16_t*)(wsf + WOFF_W1T) + d * 32768;
        fp16x8 v[4];
        #pragma unroll
        for (int j = 0; j < 4; ++j)
            #pragma unroll
            for (int e = 0; e < 8; ++e)
                v[j][e] = (fp16_t)W1[(ks * 32 + j * 8 + e) * 256 + tid];
        fp16x8* dst = (fp16x8*)(w1t + (ks * 256 + tid) * 32);
        dst[0] = v[0]; dst[1] = v[1]; dst[2] = v[2]; dst[3] = v[3];
    } else {
        const int vb = bid - 568;
        const int d = vb >> 2, q = vb & 3;
        const int w = tid >> 6, lane = tid & 63;
        const float* W2 = d ? W2b : W2f;
        float4 wr4 = ((const float4*)Wr)[lane];
        for (int it = 0; it < 16; ++it) {
            int row = q * 64 + w * 16 + it;
            float4 a = ((const float4*)(W2 + row * 256))[lane];
            float p = a.x * wr4.x + a.y * wr4.y + a.z * wr4.z + a.w * wr4.w;
            #pragma unroll
            for (int off = 32; off > 0; off >>= 1) p += __shfl_down(p, off);
            if (lane == 0) wsf[(d ? WOFF_VB : WOFF_VF) + row] = p;
        }
        if (bid == 568) {
            __shared__ float cs[4];
            float p = (b2f[tid] + b2b[tid]) * Wr[tid];
            #pragma unroll
            for (int off = 32; off > 0; off >>= 1) p += __shfl_down(p, off);
            if ((tid & 63) == 0) cs[tid >> 6] = p;
            __syncthreads();
            if (tid == 0) wsf[WOFF_CONST] = cs[0] + cs[1] + cs[2] + cs[3] + br[0];
        }
    }
}

// ---------------- fused main: M=128, 8 waves, 2-pass GEMMs (AGPR 32) ------------
// grid 2048: dir = mb&1, sp = (mb>>1)&31, bn = mb>>6. Wave w owns cols [32w,+32).
// GEMM1 split per s-half (acc 32 AGPR); conv split per N-column-tile (acc 32
// AGPR). Freed 32 regs buy depth-2 B prefetch (bq/bn1/bn2) -> L2 latency hidden
// across 2 iterations. All fragment layouts identical to R17/R18 (verified).
__global__ __launch_bounds__(512, 4) void fused_main(
    const float* __restrict__ x,
    const float* __restrict__ b1f, const float* __restrict__ Cbf,
    const float* __restrict__ b1b, const float* __restrict__ Cbb,
    const float* __restrict__ wsf,
    float* __restrict__ out) {
    __shared__ __align__(16) char hb[2 * HBUF + 1024];   // 66560 B (+OOB tail)
    __shared__ float red[128];
    __shared__ float strat_sh;

    const int tid  = threadIdx.x;
    const int w    = tid >> 6;       // 0..7
    const int lane = tid & 63;
    const int l15  = lane & 15;
    const int l4   = lane >> 4;
    const int wc   = w * 32;

    const int mb  = blockIdx.x;
    const int dir = mb & 1;
    const int sp  = (mb >> 1) & 31;
    const int bn  = mb >> 6;         // 0..31
    const int s0  = sp * 2, s1 = s0 + 1;

    // strat: wave 0 sums this b's 64 per-s count pairs (R18-verified)
    if (tid < 64) {
        const unsigned int* cthr = (const unsigned int*)wsf + WOFF_CTHR;
        const unsigned int* cpos = (const unsigned int*)wsf + WOFF_CPOS;
        unsigned int ct = cthr[(bn >> 2) * 64 + tid];
        unsigned int cp = cpos[(bn >> 2) * 64 + tid];
        #pragma unroll
        for (int off = 32; off > 0; off >>= 1) {
            ct += __shfl_down(ct, off);
            cp += __shfl_down(cp, off);
        }
        if (tid == 0) {
            float ratio = (cp > 0u) ? ((float)ct / (float)(cp < 1u ? 1u : cp)) : 0.0f;
            strat_sh = (ratio >= 0.4f) ? 1.0f : 0.0f;
        }
    }
    if (tid < 128) red[tid] = 0.0f;
    __syncthreads();
    const int strat = (strat_sh != 0.0f) ? 1 : 0;

    const float* b1 = dir ? b1b : b1f;
    const float* cbp = dir ? Cbb : Cbf;
    const float* vvp = wsf + (dir ? WOFF_VB : WOFF_VF);
    const char* w1sl = (const char*)(wsf + WOFF_W1T) + dir * 65536;
    const char* cwsl = (const char*)(wsf + WOFF_CWT) + dir * 393216;

    // ---------- stage tok f16 (both s) into hb, 256B rows, XOR-swizzled ----------
    {
        const int row_g = tid >> 2;        // 0..127
        const int half  = row_g >> 6;      // 0 -> s0, 1 -> s1
        const int row   = row_g & 63;      // lp
        const int qtr   = tid & 3;
        const int sv  = half ? s1 : s0;
        const int sg  = dir ? (63 - sv) : sv;
        const int r1i = strat ? row : sg;
        const int r2i = strat ? sg : row;
        const float* src = x + (((size_t)bn * 64 + r1i) * 8192
                                + (size_t)r2i * 128 + qtr * 32);
        char* hbt = hb + half * HBUF;
        const int rbase = row * 256 + qtr * 64;
        const int sw = (row & 7) << 4;
        #pragma unroll
        for (int j = 0; j < 4; ++j) {
            float4 p0 = *(const float4*)(src + j * 8);
            float4 p1 = *(const float4*)(src + j * 8 + 4);
            union { pkh2 h2[2]; uint2 u; } pa, pb;
            pa.h2[0] = __builtin_amdgcn_cvt_pkrtz(p0.x, p0.y);
            pa.h2[1] = __builtin_amdgcn_cvt_pkrtz(p0.z, p0.w);
            pb.h2[0] = __builtin_amdgcn_cvt_pkrtz(p1.x, p1.y);
            pb.h2[1] = __builtin_amdgcn_cvt_pkrtz(p1.z, p1.w);
            uint4 o4 = make_uint4(pa.u.x, pa.u.y, pb.u.x, pb.u.y);
            *(uint4*)(hbt + ((rbase + j * 16) ^ sw)) = o4;
        }
    }
    __syncthreads();   // tok ready

    float b1r[2][4];
    #pragma unroll
    for (int mt = 0; mt < 2; ++mt)
        #pragma unroll
        for (int q = 0; q < 4; ++q)
            b1r[mt][q] = b1[wc + mt * 16 + l4 * 4 + q];

    // ---------- GEMM1: two passes, one s-half each (acc = 32 AGPR) ---------------
    // pass0 reads tok half0 [0,16K), writes h half0 [0,32K) after barrier;
    // pass1 reads tok half1 [32K,48K) (disjoint), writes h half1 [32K,64K).
    #pragma unroll
    for (int half = 0; half < 2; ++half) {
        char* hbt = hb + half * HBUF;
        f32x4 acc1[2][4];
        #pragma unroll
        for (int i = 0; i < 2; ++i)
            #pragma unroll
            for (int j = 0; j < 4; ++j)
                acc1[i][j] = (f32x4){0.f, 0.f, 0.f, 0.f};

        #pragma unroll
        for (int ks = 0; ks < 4; ++ks) {
            fp16x8 wa[2];
            #pragma unroll
            for (int mt = 0; mt < 2; ++mt)
                wa[mt] = *(const fp16x8*)(w1sl
                    + (ks * 256 + wc + mt * 16 + l15) * 64 + l4 * 16);
            fp16x8 tb[4];
            #pragma unroll
            for (int t = 0; t < 4; ++t) {
                int row = t * 16 + l15;
                int byte = (row * 256 + ks * 64 + l4 * 16) ^ ((row & 7) << 4);
                tb[t] = *(const fp16x8*)(hbt + byte);
            }
            #pragma unroll
            for (int mt = 0; mt < 2; ++mt)
                #pragma unroll
                for (int t = 0; t < 4; ++t)
                    acc1[mt][t] = __builtin_amdgcn_mfma_f32_16x16x32_f16(
                        wa[mt], tb[t], acc1[mt][t], 0, 0, 0);
        }

        __syncthreads();  // all waves done reading this half's tok
        #pragma unroll
        for (int t = 0; t < 4; ++t) {
            int l = t * 16 + l15;
            int rowoff = l * 512;
            int sw = (l & 7) << 4;
            #pragma unroll
            for (int mt = 0; mt < 2; ++mt) {
                f32x4 a = acc1[mt][t];
                union { pkh2 h2[2]; uint2 u; } pk;
                pk.h2[0] = __builtin_amdgcn_cvt_pkrtz(
                    silu_f(a[0] + b1r[mt][0]), silu_f(a[1] + b1r[mt][1]));
                pk.h2[1] = __builtin_amdgcn_cvt_pkrtz(
                    silu_f(a[2] + b1r[mt][2]), silu_f(a[3] + b1r[mt][3]));
                int byte = (rowoff + (wc + mt * 16 + l4 * 4) * 2) ^ sw;
                *(uint2*)(hbt + byte) = pk.u;
            }
        }
    }
    __syncthreads();  // h (both halves) ready

    // ---------- conv: two N-passes (16 cols each), acc 32 AGPR, depth-2 B --------
    #pragma unroll
    for (int tp = 0; tp < 2; ++tp) {
        f32x4 acc2[8];   // [half*4 + mt]
        #pragma unroll
        for (int i = 0; i < 8; ++i)
            acc2[i] = (f32x4){0.f, 0.f, 0.f, 0.f};

        const char* cwp = cwsl + (size_t)(wc + tp * 16 + l15) * 64 + l4 * 16;
        fp16x8 bq  = *(const fp16x8*)(cwp);
        fp16x8 bn1 = *(const fp16x8*)(cwp + 16384);

        for (int ks = 0; ks < 24; ++ks) {
            fp16x8 bn2;
            if (ks < 22)
                bn2 = *(const fp16x8*)(cwp + (ks + 2) * 16384);
            const int brow = l15 + (ks >> 3);
            const int base = (brow * 512 + (ks & 7) * 64 + l4 * 16)
                             ^ ((brow & 7) << 4);
            #pragma unroll
            for (int half = 0; half < 2; ++half) {
                const char* hbt = hb + half * HBUF;
                fp16x8 af[4];
                #pragma unroll
                for (int mt = 0; mt < 4; ++mt)
                    af[mt] = *(const fp16x8*)(hbt + base + mt * 8192);
                __builtin_amdgcn_s_setprio(1);
                #pragma unroll
                for (int mt = 0; mt < 4; ++mt)
                    acc2[half * 4 + mt] = __builtin_amdgcn_mfma_f32_16x16x32_f16(
                        af[mt], bq, acc2[half * 4 + mt], 0, 0, 0);
                __builtin_amdgcn_s_setprio(0);
            }
            bq = bn1; bn1 = bn2;
        }

        // epilogue for this column tile: silu(conv + cb) * v, reduce over 16 cols
        const int col = wc + tp * 16 + l15;
        const float cbv = cbp[col];
        const float vvv = vvp[col];
        #pragma unroll
        for (int mt = 0; mt < 8; ++mt) {
            #pragma unroll
            for (int q = 0; q < 4; ++q) {
                float v0 = silu_f(acc2[mt][q] + cbv) * vvv;
                v0 += __shfl_xor(v0, 1);
                v0 += __shfl_xor(v0, 2);
                v0 += __shfl_xor(v0, 4);
                v0 += __shfl_xor(v0, 8);
                if (l15 == 0) {
                    int idx = (mt >> 2) * 64 + (mt & 3) * 16 + l4 * 4 + q;
                    atomicAdd(&red[idx], v0);
                }
            }
        }
    }

    __syncthreads();
    const float constv = dir ? 0.0f : wsf[WOFF_CONST];
    if (tid < 62)
        atomicAdd(&out[((size_t)bn * 64 + s0) * 62 + tid], red[tid] + constv);
    else if (tid >= 64 && tid < 126)
        atomicAdd(&out[((size_t)bn * 64 + s1) * 62 + (tid - 64)], red[tid] + constv);
}

extern "C" void kernel_launch(void* const* d_in, const int* in_sizes, int n_in,
                              void* d_out, int out_size, void* d_ws, size_t ws_size,
                              hipStream_t stream) {
    (void)in_sizes; (void)n_in; (void)ws_size;
    const float* x    = (const float*)d_in[0];
    const float* corr = (const float*)d_in[1];
    const float* W1f  = (const float*)d_in[2];
    const float* b1f  = (const float*)d_in[3];
    const float* Cwf  = (const float*)d_in[4];
    const float* Cbf  = (const float*)d_in[5];
    const float* W2f  = (const float*)d_in[6];
    const float* b2f  = (const float*)d_in[7];
    const float* W1b  = (const float*)d_in[8];
    const float* b1b  = (const float*)d_in[9];
    const float* Cwb  = (const float*)d_in[10];
    const float* Cbb  = (const float*)d_in[11];
    const float* W2b  = (const float*)d_in[12];
    const float* b2b  = (const float*)d_in[13];
    const float* Wr   = (const float*)d_in[14];
    const float* br   = (const float*)d_in[15];
    float* out = (float*)d_out;
    float* wsf = (float*)d_ws;

    hipMemsetAsync(out, 0, (size_t)out_size * sizeof(float), stream);
    prep_kernel<<<576, 256, 0, stream>>>(corr, W2f, b2f, W2b, b2b, Wr, br,
                                         W1f, W1b, Cwf, Cwb, wsf);
    fused_main<<<2048, 512, 0, stream>>>(x, b1f, Cbf, b1b, Cbb, wsf, out);
}

// Round 20
// 160.753 us; speedup vs baseline: 1.2700x; 1.2700x over previous
//
#include <hip/hip_runtime.h>
#include <hip/hip_bf16.h>

// ---------------- problem constants ----------------
// x: [B=8, N1=4, S=64, L=8192], PATCH=128 -> Lp=64, P=128, F=256, Lout=62
// out: [8,4,64,62,1] fp32

typedef _Float16 fp16_t;
typedef _Float16 fp16x8 __attribute__((ext_vector_type(8)));
typedef __fp16 pkh2 __attribute__((ext_vector_type(2)));   // cvt_pkrtz result type
typedef float f32x4 __attribute__((ext_vector_type(4)));

// ws float-word offsets
constexpr int WOFF_CONST = 32;    // 1 float
constexpr int WOFF_VF    = 64;    // 256 floats
constexpr int WOFF_VB    = 320;   // 256 floats
constexpr int WOFF_W1T   = 1024;                // f16 [2][4][256][32]
constexpr int WOFF_CWT   = WOFF_W1T + 32768;    // f16 [2][24][256][32] = 196608 words
constexpr int WOFF_CTHR  = WOFF_CWT + 196608;   // 512 uints, per-(b,s) cnt_thr
constexpr int WOFF_CPOS  = WOFF_CTHR + 512;     // 512 uints, per-(b,s) cnt_pos

constexpr int HBUF = 64 * 512;    // 32 KB per s-half

// silu via v_rcp (1 ulp): R13 PMC confirmed VALUBusy 52% -> 27% vs IEEE divide.
__device__ __forceinline__ float silu_f(float v) {
    return v * __builtin_amdgcn_rcpf(1.0f + __expf(-v));
}

// ---------------- prep (256 thr): rowcount + weight pack ------------------------
// bid <512   : raw-space corr counting for (b = bid>>6, s = bid&63);
//              writes per-(b,s) counts NON-atomically (no memset needed).
// bid 512-559: conv-weight slice pack; 560-567: W1 pack; 568-575: v = W2@Wr
__global__ __launch_bounds__(256) void prep_kernel(
    const float* __restrict__ c,
    const float* __restrict__ W2f, const float* __restrict__ b2f,
    const float* __restrict__ W2b, const float* __restrict__ b2b,
    const float* __restrict__ Wr,  const float* __restrict__ br,
    const float* __restrict__ W1f, const float* __restrict__ W1b,
    const float* __restrict__ Cwf, const float* __restrict__ Cwb,
    float* __restrict__ wsf) {
    const int bid = blockIdx.x;
    const int tid = threadIdx.x;

    if (bid < 512) {
        const int b = bid >> 6, s = bid & 63;
        const float* cb = c + (size_t)b * 65536;

        __shared__ __align__(16) float rowv[1024];
        __shared__ float ms_sh, ss_sh;
        __shared__ unsigned int ls[8];
        *(float4*)&rowv[tid * 4] = *(const float4*)&cb[s * 1024 + tid * 4];
        __syncthreads();

        const int t = tid >> 2, part = tid & 3;
        const float4* src  = (const float4*)(cb + t * 1024 + part * 256);
        const float4* mine = (const float4*)(rowv + part * 256);
        float dot = 0.0f, sum = 0.0f, sq = 0.0f;
        #pragma unroll 8
        for (int i = 0; i < 64; ++i) {
            float4 a = mine[i];
            float4 bb = src[i];
            dot += a.x * bb.x + a.y * bb.y + a.z * bb.z + a.w * bb.w;
            sum += bb.x + bb.y + bb.z + bb.w;
            sq  += bb.x * bb.x + bb.y * bb.y + bb.z * bb.z + bb.w * bb.w;
        }
        dot += __shfl_down(dot, 2); dot += __shfl_down(dot, 1);
        sum += __shfl_down(sum, 2); sum += __shfl_down(sum, 1);
        sq  += __shfl_down(sq, 2);  sq  += __shfl_down(sq, 1);

        float mt = 0.0f, st = 0.0f;
        if (part == 0) {
            mt = sum * (1.0f / 1024.0f);
            st = sqrtf(fmaxf((sq - 1024.0f * mt * mt) * (1.0f / 1023.0f), 0.0f));
            if (t == s) { ms_sh = mt; ss_sh = st; }
        }
        __syncthreads();
        const float ms = ms_sh, ss = ss_sh;

        const bool valid = (part == 0) && (t != s);
        const float ctr = dot - 1024.0f * ms * mt;               // 1024*cov
        unsigned long long mthr = __ballot(valid && (ctr > 0.6f * 1024.0f * ss * st));
        unsigned long long mpos = __ballot(valid && (ctr > 0.0f));
        const int w = tid >> 6;
        if ((tid & 63) == 0) {
            ls[w]     = (unsigned int)__popcll(mthr);
            ls[4 + w] = (unsigned int)__popcll(mpos);
        }
        __syncthreads();
        if (tid == 0) {
            unsigned int* cthr = (unsigned int*)wsf + WOFF_CTHR;
            unsigned int* cpos = (unsigned int*)wsf + WOFF_CPOS;
            cthr[bid] = ls[0] + ls[1] + ls[2] + ls[3];
            cpos[bid] = ls[4] + ls[5] + ls[6] + ls[7];
        }
    } else if (bid < 560) {
        const int idx = bid - 512;
        const int d = idx / 24, ks = idx % 24;
        const float* Cw = d ? Cwb : Cwf;
        fp16_t* cwt = (fp16_t*)(wsf + WOFF_CWT) + d * 196608;
        const int base = ks * 32;
        const int k = base >> 8, i0 = base & 255;
        fp16x8 v[4];
        #pragma unroll
        for (int j = 0; j < 4; ++j)
            #pragma unroll
            for (int e = 0; e < 8; ++e)
                v[j][e] = (fp16_t)Cw[(tid * 256 + i0 + j * 8 + e) * 3 + k];
        fp16x8* dst = (fp16x8*)(cwt + (ks * 256 + tid) * 32);
        dst[0] = v[0]; dst[1] = v[1]; dst[2] = v[2]; dst[3] = v[3];
    } else if (bid < 568) {
        const int sl = bid - 560;
        const int d = sl >> 2, ks = sl & 3;
        const float* W1 = d ? W1b : W1f;
        fp16_t* w1t = (fp16_t*)(wsf + WOFF_W1T) + d * 32768;
        fp16x8 v[4];
        #pragma unroll
        for (int j = 0; j < 4; ++j)
            #pragma unroll
            for (int e = 0; e < 8; ++e)
                v[j][e] = (fp16_t)W1[(ks * 32 + j * 8 + e) * 256 + tid];
        fp16x8* dst = (fp16x8*)(w1t + (ks * 256 + tid) * 32);
        dst[0] = v[0]; dst[1] = v[1]; dst[2] = v[2]; dst[3] = v[3];
    } else {
        const int vb = bid - 568;
        const int d = vb >> 2, q = vb & 3;
        const int w = tid >> 6, lane = tid & 63;
        const float* W2 = d ? W2b : W2f;
        float4 wr4 = ((const float4*)Wr)[lane];
        for (int it = 0; it < 16; ++it) {
            int row = q * 64 + w * 16 + it;
            float4 a = ((const float4*)(W2 + row * 256))[lane];
            float p = a.x * wr4.x + a.y * wr4.y + a.z * wr4.z + a.w * wr4.w;
            #pragma unroll
            for (int off = 32; off > 0; off >>= 1) p += __shfl_down(p, off);
            if (lane == 0) wsf[(d ? WOFF_VB : WOFF_VF) + row] = p;
        }
        if (bid == 568) {
            // const term, parallel over 256 threads
            __shared__ float cs[4];
            float p = (b2f[tid] + b2b[tid]) * Wr[tid];
            #pragma unroll
            for (int off = 32; off > 0; off >>= 1) p += __shfl_down(p, off);
            if ((tid & 63) == 0) cs[tid >> 6] = p;
            __syncthreads();
            if (tid == 0) wsf[WOFF_CONST] = cs[0] + cs[1] + cs[2] + cs[3] + br[0];
        }
    }
}

// ---------------- fused main: (bn, sp, dir) per block, M=128, 8 waves -----------
// R18-verified core (best measured: fused 144us, MfmaUtil 38%). R19's 2-pass
// conv variant doubled LDS A-reads (conflicts 1.6e7->2.9e7) and regressed; this
// nesting reads each A-frag once per ks and feeds both N-tiles.
__global__ __launch_bounds__(512, 4) void fused_main(
    const float* __restrict__ x,
    const float* __restrict__ b1f, const float* __restrict__ Cbf,
    const float* __restrict__ b1b, const float* __restrict__ Cbb,
    const float* __restrict__ wsf,
    float* __restrict__ out) {
    __shared__ __align__(16) char hb[2 * HBUF + 1024];   // 66560 B
    __shared__ float strat_sh;
    float* red = (float*)hb;                             // aliased post-conv

    const int tid  = threadIdx.x;
    const int w    = tid >> 6;       // 0..7
    const int lane = tid & 63;
    const int l15  = lane & 15;
    const int l4   = lane >> 4;
    const int wc   = w * 32;

    const int mb  = blockIdx.x;
    const int dir = mb & 1;
    const int sp  = (mb >> 1) & 31;
    const int bn  = mb >> 6;         // 0..31
    const int s0  = sp * 2, s1 = s0 + 1;

    // strat: wave 0 sums this b's 64 per-s count pairs
    if (tid < 64) {
        const unsigned int* cthr = (const unsigned int*)wsf + WOFF_CTHR;
        const unsigned int* cpos = (const unsigned int*)wsf + WOFF_CPOS;
        unsigned int ct = cthr[(bn >> 2) * 64 + tid];
        unsigned int cp = cpos[(bn >> 2) * 64 + tid];
        #pragma unroll
        for (int off = 32; off > 0; off >>= 1) {
            ct += __shfl_down(ct, off);
            cp += __shfl_down(cp, off);
        }
        if (tid == 0) {
            float ratio = (cp > 0u) ? ((float)ct / (float)(cp < 1u ? 1u : cp)) : 0.0f;
            strat_sh = (ratio >= 0.4f) ? 1.0f : 0.0f;
        }
    }
    __syncthreads();
    const int strat = (strat_sh != 0.0f) ? 1 : 0;

    const float* b1 = dir ? b1b : b1f;
    const float* cbp = dir ? Cbb : Cbf;
    const char* w1sl = (const char*)(wsf + WOFF_W1T) + dir * 65536;
    const char* cwsl = (const char*)(wsf + WOFF_CWT) + dir * 393216;

    // ---------- stage tok f16 (both s) into hb, 256B rows, XOR-swizzled ----------
    {
        const int row_g = tid >> 2;        // 0..127
        const int half  = row_g >> 6;      // 0 -> s0, 1 -> s1
        const int row   = row_g & 63;      // lp
        const int qtr   = tid & 3;
        const int sv  = half ? s1 : s0;
        const int sg  = dir ? (63 - sv) : sv;
        const int r1i = strat ? row : sg;
        const int r2i = strat ? sg : row;
        const float* src = x + (((size_t)bn * 64 + r1i) * 8192
                                + (size_t)r2i * 128 + qtr * 32);
        char* hbt = hb + half * HBUF;
        const int rbase = row * 256 + qtr * 64;
        const int sw = (row & 7) << 4;
        #pragma unroll
        for (int j = 0; j < 4; ++j) {
            float4 p0 = *(const float4*)(src + j * 8);
            float4 p1 = *(const float4*)(src + j * 8 + 4);
            union { pkh2 h2[2]; uint2 u; } pa, pb;
            pa.h2[0] = __builtin_amdgcn_cvt_pkrtz(p0.x, p0.y);
            pa.h2[1] = __builtin_amdgcn_cvt_pkrtz(p0.z, p0.w);
            pb.h2[0] = __builtin_amdgcn_cvt_pkrtz(p1.x, p1.y);
            pb.h2[1] = __builtin_amdgcn_cvt_pkrtz(p1.z, p1.w);
            uint4 o4 = make_uint4(pa.u.x, pa.u.y, pb.u.x, pb.u.y);
            *(uint4*)(hbt + ((rbase + j * 16) ^ sw)) = o4;
        }
    }
    __syncthreads();   // tok ready

    // ---------- GEMM1 (swapped): h[l][f] = silu(tok@W1 + b1), both s -------------
    f32x4 acc1[2][8];
    #pragma unroll
    for (int i = 0; i < 2; ++i)
        #pragma unroll
        for (int j = 0; j < 8; ++j)
            acc1[i][j] = (f32x4){0.f, 0.f, 0.f, 0.f};

    #pragma unroll
    for (int ks = 0; ks < 4; ++ks) {
        fp16x8 wa[2];   // A = W1 frags (M = f, wave's 32 cols)
        #pragma unroll
        for (int mt = 0; mt < 2; ++mt)
            wa[mt] = *(const fp16x8*)(w1sl
                + (ks * 256 + wc + mt * 16 + l15) * 64 + l4 * 16);
        #pragma unroll
        for (int half = 0; half < 2; ++half) {   // half-split keeps tb at 4 regs
            const char* hbt = hb + half * HBUF;
            fp16x8 tb[4];
            #pragma unroll
            for (int t = 0; t < 4; ++t) {
                int row = t * 16 + l15;
                int byte = (row * 256 + ks * 64 + l4 * 16) ^ ((row & 7) << 4);
                tb[t] = *(const fp16x8*)(hbt + byte);
            }
            #pragma unroll
            for (int mt = 0; mt < 2; ++mt)
                #pragma unroll
                for (int t = 0; t < 4; ++t)
                    acc1[mt][half * 4 + t] = __builtin_amdgcn_mfma_f32_16x16x32_f16(
                        wa[mt], tb[t], acc1[mt][half * 4 + t], 0, 0, 0);
        }
    }

    float b1r[2][4];
    #pragma unroll
    for (int mt = 0; mt < 2; ++mt)
        #pragma unroll
        for (int q = 0; q < 4; ++q)
            b1r[mt][q] = b1[wc + mt * 16 + l4 * 4 + q];

    __syncthreads();  // all tok reads done before overwrite
    #pragma unroll
    for (int t = 0; t < 8; ++t) {
        char* hbt = hb + (t >> 2) * HBUF;
        int l = (t & 3) * 16 + l15;
        int rowoff = l * 512;
        int sw = (l & 7) << 4;
        #pragma unroll
        for (int mt = 0; mt < 2; ++mt) {
            f32x4 a = acc1[mt][t];
            union { pkh2 h2[2]; uint2 u; } pk;
            pk.h2[0] = __builtin_amdgcn_cvt_pkrtz(
                silu_f(a[0] + b1r[mt][0]), silu_f(a[1] + b1r[mt][1]));
            pk.h2[1] = __builtin_amdgcn_cvt_pkrtz(
                silu_f(a[2] + b1r[mt][2]), silu_f(a[3] + b1r[mt][3]));
            int byte = (rowoff + (wc + mt * 16 + l4 * 4) * 2) ^ sw;
            *(uint2*)(hbt + byte) = pk.u;
        }
    }
    __syncthreads();  // h ready

    // ---------- conv GEMM: M=128 (2 s), K=768, 24 slices, depth-1 B prefetch -----
    f32x4 acc2[8][2];
    #pragma unroll
    for (int i = 0; i < 8; ++i)
        #pragma unroll
        for (int j = 0; j < 2; ++j)
            acc2[i][j] = (f32x4){0.f, 0.f, 0.f, 0.f};

    const char* cw_w = cwsl + (size_t)(wc + l15) * 64 + l4 * 16;
    fp16x8 bq[2];
    #pragma unroll
    for (int t = 0; t < 2; ++t)
        bq[t] = *(const fp16x8*)(cw_w + t * 1024);

    for (int ks = 0; ks < 24; ++ks) {
        fp16x8 bnx[2];
        if (ks < 23) {
            #pragma unroll
            for (int t = 0; t < 2; ++t)
                bnx[t] = *(const fp16x8*)(cw_w + (ks + 1) * 16384 + t * 1024);
        }
        const int brow = l15 + (ks >> 3);
        const int base = (brow * 512 + (ks & 7) * 64 + l4 * 16)
                         ^ ((brow & 7) << 4);
        #pragma unroll
        for (int half = 0; half < 2; ++half) {   // half-split keeps af at 4 regs
            const char* hbt = hb + half * HBUF;
            fp16x8 af[4];
            #pragma unroll
            for (int mt = 0; mt < 4; ++mt)
                af[mt] = *(const fp16x8*)(hbt + base + mt * 8192);
            __builtin_amdgcn_s_setprio(1);
            #pragma unroll
            for (int t = 0; t < 2; ++t)
                #pragma unroll
                for (int mt = 0; mt < 4; ++mt)
                    acc2[half * 4 + mt][t] = __builtin_amdgcn_mfma_f32_16x16x32_f16(
                        af[mt], bq[t], acc2[half * 4 + mt][t], 0, 0, 0);
            __builtin_amdgcn_s_setprio(0);
        }
        #pragma unroll
        for (int t = 0; t < 2; ++t) bq[t] = bnx[t];
    }

    // red aliases hb -- conv reads done; zero, then accumulate
    __syncthreads();
    if (tid < 128) red[tid] = 0.0f;
    __syncthreads();

    // epilogue: silu(conv + cb) * v, reduce over o -> red
    float cbv[2], vv[2];
    #pragma unroll
    for (int t = 0; t < 2; ++t) {
        int col = wc + t * 16 + l15;
        cbv[t] = cbp[col];
        vv[t]  = wsf[(dir ? WOFF_VB : WOFF_VF) + col];
    }
    #pragma unroll
    for (int mt = 0; mt < 8; ++mt) {
        #pragma unroll
        for (int q = 0; q < 4; ++q) {
            float v0 = 0.f;
            #pragma unroll
            for (int t = 0; t < 2; ++t)
                v0 += silu_f(acc2[mt][t][q] + cbv[t]) * vv[t];
            v0 += __shfl_xor(v0, 1);
            v0 += __shfl_xor(v0, 2);
            v0 += __shfl_xor(v0, 4);
            v0 += __shfl_xor(v0, 8);
            if (l15 == 0) {
                int idx = (mt >> 2) * 64 + (mt & 3) * 16 + l4 * 4 + q;
                atomicAdd(&red[idx], v0);
            }
        }
    }

    __syncthreads();
    const float constv = dir ? 0.0f : wsf[WOFF_CONST];
    if (tid < 62)
        atomicAdd(&out[((size_t)bn * 64 + s0) * 62 + tid], red[tid] + constv);
    else if (tid >= 64 && tid < 126)
        atomicAdd(&out[((size_t)bn * 64 + s1) * 62 + (tid - 64)], red[tid] + constv);
}

extern "C" void kernel_launch(void* const* d_in, const int* in_sizes, int n_in,
                              void* d_out, int out_size, void* d_ws, size_t ws_size,
                              hipStream_t stream) {
    (void)in_sizes; (void)n_in; (void)ws_size;
    const float* x    = (const float*)d_in[0];
    const float* corr = (const float*)d_in[1];
    const float* W1f  = (const float*)d_in[2];
    const float* b1f  = (const float*)d_in[3];
    const float* Cwf  = (const float*)d_in[4];
    const float* Cbf  = (const float*)d_in[5];
    const float* W2f  = (const float*)d_in[6];
    const float* b2f  = (const float*)d_in[7];
    const float* W1b  = (const float*)d_in[8];
    const float* b1b  = (const float*)d_in[9];
    const float* Cwb  = (const float*)d_in[10];
    const float* Cbb  = (const float*)d_in[11];
    const float* W2b  = (const float*)d_in[12];
    const float* b2b  = (const float*)d_in[13];
    const float* Wr   = (const float*)d_in[14];
    const float* br   = (const float*)d_in[15];
    float* out = (float*)d_out;
    float* wsf = (float*)d_ws;

    hipMemsetAsync(out, 0, (size_t)out_size * sizeof(float), stream);
    prep_kernel<<<576, 256, 0, stream>>>(corr, W2f, b2f, W2b, b2b, Wr, br,
                                         W1f, W1b, Cwf, Cwb, wsf);
    fused_main<<<2048, 512, 0, stream>>>(x, b1f, Cbf, b1b, Cbb, wsf, out);
}